// Round 10
// baseline (331.992 us; speedup 1.0000x reference)
//
#include <hip/hip_runtime.h>
#include <cstdint>

// MambaBlock: out = (silu(x@in_w[:1024]^T+b0) * silu(x@in_w[1024:]^T+b1)) @ out_w^T + out_b
// M = 32768, K = 1024. dt_w/dt_b/A/Dp are dead inputs.
//
// Round 10 = round 6/9 verified GEMM core + x-cast fused into GEMM1 via
// reg-staged A (fp32 global_load -> cvt -> swizzled ds_write), removing the
// 134+67 MB x cast round-trip. B stays on global_load_lds. Ledger: per phase
// [dswr A(k+1) | ldA(k+2) | FENCE | B-gl(k+2)]; vmcnt(2) at phase top retires
// B(k) (2-phase lead) and A-loads(k+1) (1-phase lead); FENCE pins issue order;
// WAITBL adds lgkmcnt(0) for ds_write visibility across the barrier.
// Core: 256x256 tile, BK=32, 8 waves 2Mx4N, 3 LDS bufs (96 KiB, 1 block/CU),
// 32x32x16 MFMA, swizzle key2(row)=((row>>1)^(row>>4))&3 (0 conflicts),
// setprio, bijective XCD swizzle, shuffle-free paired-silu epilogue.
// r7 lesson: acc[4][4]x16 spills -> 25x slowdown. r8 lesson: launch_bounds
// (512,4) clamps VGPR -> spill; 1 block/CU is the design point.

typedef __bf16 bf16x8 __attribute__((ext_vector_type(8)));
typedef float f32x16 __attribute__((ext_vector_type(16)));

#define KD 1024
#define BUF_ELEMS 16384  // (256*32 A + 256*32 B) elems per buffer

__device__ __forceinline__ void gload_lds16(const void* g, void* lds_u) {
  __builtin_amdgcn_global_load_lds(
      (__attribute__((address_space(1))) void*)(uintptr_t)g,
      (__attribute__((address_space(3))) void*)(uint32_t)(uintptr_t)lds_u,
      16, 0, 0);
}

#define WAITB(N) do { \
  asm volatile("s_waitcnt vmcnt(" #N ")" ::: "memory"); \
  asm volatile("s_barrier" ::: "memory"); } while (0)

// GEMM1 variant: also drain lgkm so reg-staged ds_writes are barrier-visible.
#define WAITBL(N) do { \
  asm volatile("s_waitcnt vmcnt(" #N ") lgkmcnt(0)" ::: "memory"); \
  asm volatile("s_barrier" ::: "memory"); } while (0)

#define FENCE asm volatile("" ::: "memory")

// ---------------- weights cast kernel ----------------
// blocks [0,1024): in_w -> w1b with 32-row block interleave; [1024,1536): out_w -> w2b
__global__ void cast_weights(const float* __restrict__ in_w, __bf16* __restrict__ w1b,
                             const float* __restrict__ out_w, __bf16* __restrict__ w2b) {
  const int b = blockIdx.x;
  if (b < 1024) {
    // W1'' 32-row block interleave: out-row r, blk=r>>5, t=r&31:
    //   src row = (blk&1)*1024 + (blk>>1)*32 + t
    int i = b * 256 + threadIdx.x;  // 2048*128 threads
    int orow = i >> 7;
    int chunk = i & 127;
    int bb = orow >> 5, t = orow & 31;
    int srow = (bb & 1) * 1024 + (bb >> 1) * 32 + t;
    const float4* p = (const float4*)(in_w + ((size_t)srow << 10) + (chunk << 3));
    float4 v0 = p[0], v1 = p[1];
    bf16x8 o;
    o[0] = (__bf16)v0.x; o[1] = (__bf16)v0.y; o[2] = (__bf16)v0.z; o[3] = (__bf16)v0.w;
    o[4] = (__bf16)v1.x; o[5] = (__bf16)v1.y; o[6] = (__bf16)v1.z; o[7] = (__bf16)v1.w;
    *(bf16x8*)(w1b + ((size_t)orow << 10) + (chunk << 3)) = o;
  } else {
    int i = (b - 1024) * 256 + threadIdx.x;  // < 131072 = 1048576/8
    const float4* p = (const float4*)out_w;
    float4 v0 = p[2 * i];
    float4 v1 = p[2 * i + 1];
    bf16x8 o;
    o[0] = (__bf16)v0.x; o[1] = (__bf16)v0.y; o[2] = (__bf16)v0.z; o[3] = (__bf16)v0.w;
    o[4] = (__bf16)v1.x; o[5] = (__bf16)v1.y; o[6] = (__bf16)v1.z; o[7] = (__bf16)v1.w;
    ((bf16x8*)w2b)[i] = o;
  }
}

// ---------------- shared GEMM pieces ----------------
// B-staging: one 256x32 half (B region) of tile into buffer BUF. 2 gloads/wave.
template <int BUF>
__device__ __forceinline__ void stageB(const __bf16*& pb, __bf16* smwB) {
  __bf16* d = smwB + BUF * BUF_ELEMS;
  gload_lds16(pb, d);
  gload_lds16(pb + 128 * KD, d + 4096);
  pb += 32;
}

// A-staging via gload_lds (GEMM2 path).
template <int BUF>
__device__ __forceinline__ void stageA_g(const __bf16*& pa, __bf16* smwA) {
  __bf16* d = smwA + BUF * BUF_ELEMS;
  gload_lds16(pa, d);
  gload_lds16(pa + 128 * KD, d + 4096);
  pa += 32;
}

// A-staging via registers (GEMM1 path): 4x float4 fp32 loads.
__device__ __forceinline__ void ldA(float4 (&r)[4], const float* p) {
  r[0] = *(const float4*)p;
  r[1] = *(const float4*)(p + 4);
  r[2] = *(const float4*)(p + 128 * 1024);
  r[3] = *(const float4*)(p + 128 * 1024 + 4);
}

template <int BUF>
__device__ __forceinline__ void dswrA(const float4 (&r)[4], __bf16* dwA) {
  __bf16* d = dwA + BUF * BUF_ELEMS;
  bf16x8 lo, hi;
  lo[0] = (__bf16)r[0].x; lo[1] = (__bf16)r[0].y; lo[2] = (__bf16)r[0].z; lo[3] = (__bf16)r[0].w;
  lo[4] = (__bf16)r[1].x; lo[5] = (__bf16)r[1].y; lo[6] = (__bf16)r[1].z; lo[7] = (__bf16)r[1].w;
  hi[0] = (__bf16)r[2].x; hi[1] = (__bf16)r[2].y; hi[2] = (__bf16)r[2].z; hi[3] = (__bf16)r[2].w;
  hi[4] = (__bf16)r[3].x; hi[5] = (__bf16)r[3].y; hi[6] = (__bf16)r[3].z; hi[7] = (__bf16)r[3].w;
  *(bf16x8*)d = lo;
  *(bf16x8*)(d + 4096) = hi;
}

// 32x32x16 MFMA. Per K-tile-32: 2 k-slices; 8 A + 4 B b128 reads; 16 MFMA.
template <int BUF>
__device__ __forceinline__ void compute_tile(const __bf16* sm,
                                             int aRow, int bRow,
                                             int o0, int o1,
                                             f32x16 (&acc)[4][2]) {
  const __bf16* base = sm + BUF * BUF_ELEMS;
  bf16x8 a0[4], a1[4], b0[2], b1[2];
  // j even: ks0 -> o0, ks1 -> o1 ; j odd: swapped
  b0[0] = *(const bf16x8*)(base + bRow + o0);
  b1[0] = *(const bf16x8*)(base + bRow + o1);
  b0[1] = *(const bf16x8*)(base + bRow + 1024 + o1);
  b1[1] = *(const bf16x8*)(base + bRow + 1024 + o0);
#pragma unroll
  for (int i = 0; i < 4; ++i) {
    const int e0 = (i & 1) ? o1 : o0;
    const int e1 = (i & 1) ? o0 : o1;
    a0[i] = *(const bf16x8*)(base + aRow + i * 1024 + e0);
    a1[i] = *(const bf16x8*)(base + aRow + i * 1024 + e1);
  }
  __builtin_amdgcn_s_setprio(1);
#pragma unroll
  for (int i = 0; i < 4; ++i)
#pragma unroll
    for (int j = 0; j < 2; ++j)
      acc[i][j] = __builtin_amdgcn_mfma_f32_32x32x16_bf16(a0[i], b0[j], acc[i][j], 0, 0, 0);
#pragma unroll
  for (int i = 0; i < 4; ++i)
#pragma unroll
    for (int j = 0; j < 2; ++j)
      acc[i][j] = __builtin_amdgcn_mfma_f32_32x32x16_bf16(a1[i], b1[j], acc[i][j], 0, 0, 0);
  __builtin_amdgcn_s_setprio(0);
}

// ---------------- GEMM1 core: fp32 A (reg-staged) x bf16 B ----------------
__device__ __forceinline__ void gemm1_core(const float* __restrict__ X32,
                                           const __bf16* __restrict__ B,
                                           __bf16* sm, long m0, long n0,
                                           f32x16 (&acc)[4][2]) {
  const int t = threadIdx.x;
  const int w = t >> 6;
  const int lane = t & 63;
  const int c31 = lane & 31;
  const int hi = lane >> 5;
  const int wr = w >> 2;
  const int wc = w & 3;
  const int l = lane;

  // B staging source (pre-swizzled chunk, as r6): key2 = ((l>>3)&3)^(w&3)
  const int stg_row = w * 16 + (l >> 2);
  const int stg_col = ((l & 3) ^ ((l >> 3) & 3) ^ (w & 3)) << 3;
  const __bf16* pb = B + (n0 + stg_row) * KD + stg_col;
  __bf16* smwB = sm + 8192 + w * 512;

  // A staging: unswizzled contiguous fp32 source; swizzle applied on ds_write.
  const float* pxk = X32 + (m0 + stg_row) * 1024 + (l & 3) * 8;
  const int aphys = (l & 3) ^ ((l >> 3) & 3) ^ (w & 3);
  __bf16* dwA = sm + stg_row * 32 + aphys * 8;

  // fragment read offsets (identical to r6)
  const int key_base = ((c31 >> 1) & 3) ^ ((c31 >> 4) & 1);
  const int o0 = (hi ^ key_base) << 3;
  const int o1 = o0 ^ 16;
  const int aRow = (wr * 128 + c31) * 32;
  const int bRow = 8192 + (wc * 64 + c31) * 32;

#pragma unroll
  for (int i = 0; i < 4; ++i)
#pragma unroll
    for (int j = 0; j < 2; ++j)
      acc[i][j] = (f32x16){0.f, 0.f, 0.f, 0.f, 0.f, 0.f, 0.f, 0.f,
                           0.f, 0.f, 0.f, 0.f, 0.f, 0.f, 0.f, 0.f};

  float4 rA[4];
  // prologue: issue A(0), B(0); retire A(0); dswr A(0); issue A(1), B(1)
  ldA(rA, pxk); pxk += 32;
  FENCE;
  stageB<0>(pb, smwB);
  asm volatile("s_waitcnt vmcnt(2)" ::: "memory");
  dswrA<0>(rA, dwA);
  ldA(rA, pxk); pxk += 32;
  FENCE;
  stageB<1>(pb, smwB);

  // phases 0..29 (tile k in buf k%3): WAITBL(2) retires B(k) and A-lds(k+1);
  // dswr A(k+1) -> buf (k+1)%3; issue A-lds(k+2); stage B(k+2) -> buf (k+2)%3.
  for (int it = 0; it < 10; ++it) {
    WAITBL(2);
    dswrA<1>(rA, dwA);
    ldA(rA, pxk); pxk += 32;
    FENCE;
    stageB<2>(pb, smwB);
    compute_tile<0>(sm, aRow, bRow, o0, o1, acc);
    WAITBL(2);
    dswrA<2>(rA, dwA);
    ldA(rA, pxk); pxk += 32;
    FENCE;
    stageB<0>(pb, smwB);
    compute_tile<1>(sm, aRow, bRow, o0, o1, acc);
    WAITBL(2);
    dswrA<0>(rA, dwA);
    ldA(rA, pxk); pxk += 32;
    FENCE;
    stageB<1>(pb, smwB);
    compute_tile<2>(sm, aRow, bRow, o0, o1, acc);
  }
  // phase 30: dswr A(31) -> buf1; compute(30) in buf0. (outstanding: B30,A31,B31)
  WAITBL(2);
  dswrA<1>(rA, dwA);
  compute_tile<0>(sm, aRow, bRow, o0, o1, acc);
  // phase 31: compute(31) in buf1.
  WAITBL(0);
  compute_tile<1>(sm, aRow, bRow, o0, o1, acc);
}

// ---------------- GEMM2 core: bf16 A via gload_lds (r6 verified) -----------
__device__ __forceinline__ void gemm_core(const __bf16* __restrict__ A,
                                          const __bf16* __restrict__ B,
                                          __bf16* sm, long m0, long n0,
                                          f32x16 (&acc)[4][2]) {
  const int t = threadIdx.x;
  const int w = t >> 6;
  const int lane = t & 63;
  const int c31 = lane & 31;
  const int hi = lane >> 5;
  const int wr = w >> 2;
  const int wc = w & 3;
  const int l = lane;

  const int stg_row = w * 16 + (l >> 2);
  const int stg_col = ((l & 3) ^ ((l >> 3) & 3) ^ (w & 3)) << 3;
  const __bf16* pa = A + (m0 + stg_row) * KD + stg_col;
  const __bf16* pb = B + (n0 + stg_row) * KD + stg_col;
  __bf16* smwA = sm + w * 512;
  __bf16* smwB = sm + 8192 + w * 512;

  const int key_base = ((c31 >> 1) & 3) ^ ((c31 >> 4) & 1);
  const int o0 = (hi ^ key_base) << 3;
  const int o1 = o0 ^ 16;
  const int aRow = (wr * 128 + c31) * 32;
  const int bRow = 8192 + (wc * 64 + c31) * 32;

#pragma unroll
  for (int i = 0; i < 4; ++i)
#pragma unroll
    for (int j = 0; j < 2; ++j)
      acc[i][j] = (f32x16){0.f, 0.f, 0.f, 0.f, 0.f, 0.f, 0.f, 0.f,
                           0.f, 0.f, 0.f, 0.f, 0.f, 0.f, 0.f, 0.f};

  stageA_g<0>(pa, smwA); stageB<0>(pb, smwB);
  stageA_g<1>(pa, smwA); stageB<1>(pb, smwB);

  for (int it = 0; it < 10; ++it) {
    WAITB(4); stageA_g<2>(pa, smwA); stageB<2>(pb, smwB);
    compute_tile<0>(sm, aRow, bRow, o0, o1, acc);
    WAITB(4); stageA_g<0>(pa, smwA); stageB<0>(pb, smwB);
    compute_tile<1>(sm, aRow, bRow, o0, o1, acc);
    WAITB(4); stageA_g<1>(pa, smwA); stageB<1>(pb, smwB);
    compute_tile<2>(sm, aRow, bRow, o0, o1, acc);
  }
  WAITB(4); compute_tile<0>(sm, aRow, bRow, o0, o1, acc);
  WAITB(0); compute_tile<1>(sm, aRow, bRow, o0, o1, acc);
}

// ---------------- GEMM1: Y = X(fp32) @ W1''^T, paired-silu -> G bf16 --------
__global__ __launch_bounds__(512, 2)
void gemm1_silu(const float* __restrict__ X32, const __bf16* __restrict__ W1i,
                const float* __restrict__ in_b, __bf16* __restrict__ G) {
  __shared__ __bf16 sm[3 * BUF_ELEMS];
  const int bid = blockIdx.x;  // nwg = 1024
  const int swz = (bid & 7) * 128 + (bid >> 3);
  const long m0 = (long)(swz >> 3) * 256;
  const long n0 = (long)(swz & 7) * 256;

  f32x16 acc[4][2];
  gemm1_core(X32, W1i, sm, m0, n0, acc);

  const int lane = threadIdx.x & 63;
  const int w = threadIdx.x >> 6;
  const int wr = w >> 2, wc = w & 3;
  const int c31 = lane & 31;
  const int hi = lane >> 5;

  const int gc = ((int)n0 >> 1) + wc * 32 + c31;
  const float bx = in_b[gc];
  const float br = in_b[1024 + gc];

#pragma unroll
  for (int i = 0; i < 4; ++i)
#pragma unroll
    for (int reg = 0; reg < 16; ++reg) {
      const int row = wr * 128 + i * 32 + (reg & 3) + 8 * (reg >> 2) + 4 * hi;
      float xv = acc[i][0][reg] + bx;
      float rs = acc[i][1][reg] + br;
      float e1 = __expf(-xv);
      float e2 = __expf(-rs);
      float g = xv * rs * __builtin_amdgcn_rcpf((1.0f + e1) * (1.0f + e2));
      G[(m0 + row) * 1024 + gc] = (__bf16)g;
    }
}

// ---------------- GEMM2: OUT = G @ W2^T + out_b (fp32) ----------------
__global__ __launch_bounds__(512, 2)
void gemm2_bias(const __bf16* __restrict__ G, const __bf16* __restrict__ W2,
                const float* __restrict__ out_b, float* __restrict__ OUT) {
  __shared__ __bf16 sm[3 * BUF_ELEMS];
  const int bid = blockIdx.x;  // nwg = 512
  const int swz = (bid & 7) * 64 + (bid >> 3);
  const long m0 = (long)(swz >> 2) * 256;
  const long n0 = (long)(swz & 3) * 256;

  f32x16 acc[4][2];
  gemm_core(G, W2, sm, m0, n0, acc);

  const int lane = threadIdx.x & 63;
  const int w = threadIdx.x >> 6;
  const int wr = w >> 2, wc = w & 3;
  const int c31 = lane & 31;
  const int hi = lane >> 5;

  float ob[2];
#pragma unroll
  for (int j = 0; j < 2; ++j)
    ob[j] = out_b[(int)n0 + wc * 64 + j * 32 + c31];
#pragma unroll
  for (int i = 0; i < 4; ++i)
#pragma unroll
    for (int j = 0; j < 2; ++j)
#pragma unroll
      for (int reg = 0; reg < 16; ++reg) {
        const int row = wr * 128 + i * 32 + (reg & 3) + 8 * (reg >> 2) + 4 * hi;
        const int col = (int)n0 + wc * 64 + j * 32 + c31;
        OUT[(m0 + row) * 1024 + col] = acc[i][j][reg] + ob[j];
      }
}

extern "C" void kernel_launch(void* const* d_in, const int* in_sizes, int n_in,
                              void* d_out, int out_size, void* d_ws, size_t ws_size,
                              hipStream_t stream) {
  const float* x = (const float*)d_in[0];
  const float* in_w = (const float*)d_in[1];
  const float* in_b = (const float*)d_in[2];
  const float* out_w = (const float*)d_in[3];
  const float* out_b = (const float*)d_in[4];
  // d_in[5..8] (dt_w, dt_b, A, Dp) are dead in the reference.

  char* ws = (char*)d_ws;
  __bf16* w1b = (__bf16*)(ws);                      // 4194304 B (blk32 interleaved)
  __bf16* w2b = (__bf16*)(ws + (size_t)4194304);    // 2097152 B
  __bf16* gb = (__bf16*)(ws + (size_t)6291456);     // 67108864 B

  cast_weights<<<dim3(1536), 256, 0, stream>>>(in_w, w1b, out_w, w2b);
  gemm1_silu<<<dim3(1024), 512, 0, stream>>>(x, w1b, in_b, gb);
  gemm2_bias<<<dim3(512), 512, 0, stream>>>(gb, w2b, out_b, (float*)d_out);
}

// Round 11
// 261.370 us; speedup vs baseline: 1.2702x; 1.2702x over previous
//
#include <hip/hip_runtime.h>
#include <cstdint>

// MambaBlock: out = (silu(x@in_w[:1024]^T+b0) * silu(x@in_w[1024:]^T+b1)) @ out_w^T + out_b
// M = 32768, K = 1024. dt_w/dt_b/A/Dp are dead inputs.
//
// Round 11 = round 9 verified optimum (261.0 us), restored after r10's
// fused-A-cast regression (fp32 A doubles L2 traffic; mixed vmcnt stream +
// lgkm drain collapses prefetch; cvt on critical path).
// Core: 256x256 tile, BK=32, 512 threads (8 waves, 2Mx4N), triple-buffered LDS
// (96 KiB, 1 block/CU), prefetch depth 2, counted vmcnt(4), 32x32x16 MFMA,
// swizzle key2(row)=((row>>1)^(row>>4))&3 on both stage-source and ds_read
// (measured 0 bank conflicts), setprio around MFMA cluster, bijective XCD
// swizzle, shuffle-free paired-silu epilogue (blk32-interleaved W1),
// single merged cast launch.
// Design-space ledger: r7 fat tile -> spill (25x); r8 2 blocks/CU -> VGPR
// clamp spill; r3/r4 schedule splits -> null; r10 A-cast fusion -> -71 us.

typedef __bf16 bf16x8 __attribute__((ext_vector_type(8)));
typedef float f32x16 __attribute__((ext_vector_type(16)));

#define KD 1024
#define BUF_ELEMS 16384  // (256*32 A + 256*32 B) elems per buffer

__device__ __forceinline__ void gload_lds16(const void* g, void* lds_u) {
  __builtin_amdgcn_global_load_lds(
      (__attribute__((address_space(1))) void*)(uintptr_t)g,
      (__attribute__((address_space(3))) void*)(uint32_t)(uintptr_t)lds_u,
      16, 0, 0);
}

#define WAITB(N) do { \
  asm volatile("s_waitcnt vmcnt(" #N ")" ::: "memory"); \
  asm volatile("s_barrier" ::: "memory"); } while (0)

// ---------------- merged cast kernel (single launch) ----------------
// blocks [0, 16384): x -> xb (f32->bf16, 8 elems/thread)
// blocks [16384, 17408): in_w -> w1b with 32-row block interleave
// blocks [17408, 17920): out_w -> w2b
__global__ void cast_all(const float* __restrict__ x, __bf16* __restrict__ xb,
                         const float* __restrict__ in_w, __bf16* __restrict__ w1b,
                         const float* __restrict__ out_w, __bf16* __restrict__ w2b) {
  const int b = blockIdx.x;
  if (b < 16384) {
    int i = b * 256 + threadIdx.x;  // < 4194304 = 33554432/8
    const float4* p = (const float4*)x;
    float4 v0 = p[2 * i];
    float4 v1 = p[2 * i + 1];
    bf16x8 o;
    o[0] = (__bf16)v0.x; o[1] = (__bf16)v0.y; o[2] = (__bf16)v0.z; o[3] = (__bf16)v0.w;
    o[4] = (__bf16)v1.x; o[5] = (__bf16)v1.y; o[6] = (__bf16)v1.z; o[7] = (__bf16)v1.w;
    ((bf16x8*)xb)[i] = o;
  } else if (b < 17408) {
    // W1'' 32-row block interleave: out-row r, blk=r>>5, t=r&31:
    //   src row = (blk&1)*1024 + (blk>>1)*32 + t
    int i = (b - 16384) * 256 + threadIdx.x;  // 2048*128 threads
    int orow = i >> 7;
    int chunk = i & 127;
    int bb = orow >> 5, t = orow & 31;
    int srow = (bb & 1) * 1024 + (bb >> 1) * 32 + t;
    const float4* p = (const float4*)(in_w + ((size_t)srow << 10) + (chunk << 3));
    float4 v0 = p[0], v1 = p[1];
    bf16x8 o;
    o[0] = (__bf16)v0.x; o[1] = (__bf16)v0.y; o[2] = (__bf16)v0.z; o[3] = (__bf16)v0.w;
    o[4] = (__bf16)v1.x; o[5] = (__bf16)v1.y; o[6] = (__bf16)v1.z; o[7] = (__bf16)v1.w;
    *(bf16x8*)(w1b + ((size_t)orow << 10) + (chunk << 3)) = o;
  } else {
    int i = (b - 17408) * 256 + threadIdx.x;  // < 131072 = 1048576/8
    const float4* p = (const float4*)out_w;
    float4 v0 = p[2 * i];
    float4 v1 = p[2 * i + 1];
    bf16x8 o;
    o[0] = (__bf16)v0.x; o[1] = (__bf16)v0.y; o[2] = (__bf16)v0.z; o[3] = (__bf16)v0.w;
    o[4] = (__bf16)v1.x; o[5] = (__bf16)v1.y; o[6] = (__bf16)v1.z; o[7] = (__bf16)v1.w;
    ((bf16x8*)w2b)[i] = o;
  }
}

// ---------------- GEMM core ----------------
// Stage one 256x32 K-tile of A and B into buffer BUF. 4 gloads per wave.
template <int BUF>
__device__ __forceinline__ void stage_tile(const __bf16*& pa, const __bf16*& pb,
                                           __bf16* smw) {
  __bf16* d = smw + BUF * BUF_ELEMS;
  gload_lds16(pa, d);
  gload_lds16(pa + 128 * KD, d + 4096);
  gload_lds16(pb, d + 8192);
  gload_lds16(pb + 128 * KD, d + 12288);
  pa += 32;
  pb += 32;
}

// 32x32x16 MFMA. Per K-tile-32: 2 k-slices; 8 A + 4 B b128 reads; 16 MFMA.
// Chunk swizzle: phys = logical ^ key2(row); per frag parity the chunk offset
// alternates between o0 and o1 = o0^16 (key2 flips by 2 when frag idx is odd).
template <int BUF>
__device__ __forceinline__ void compute_tile(const __bf16* sm,
                                             int aRow, int bRow,
                                             int o0, int o1,
                                             f32x16 (&acc)[4][2]) {
  const __bf16* base = sm + BUF * BUF_ELEMS;
  bf16x8 a0[4], a1[4], b0[2], b1[2];
  // j even: ks0 -> o0, ks1 -> o1 ; j odd: swapped
  b0[0] = *(const bf16x8*)(base + bRow + o0);
  b1[0] = *(const bf16x8*)(base + bRow + o1);
  b0[1] = *(const bf16x8*)(base + bRow + 1024 + o1);
  b1[1] = *(const bf16x8*)(base + bRow + 1024 + o0);
#pragma unroll
  for (int i = 0; i < 4; ++i) {
    const int e0 = (i & 1) ? o1 : o0;
    const int e1 = (i & 1) ? o0 : o1;
    a0[i] = *(const bf16x8*)(base + aRow + i * 1024 + e0);
    a1[i] = *(const bf16x8*)(base + aRow + i * 1024 + e1);
  }
  __builtin_amdgcn_s_setprio(1);
#pragma unroll
  for (int i = 0; i < 4; ++i)
#pragma unroll
    for (int j = 0; j < 2; ++j)
      acc[i][j] = __builtin_amdgcn_mfma_f32_32x32x16_bf16(a0[i], b0[j], acc[i][j], 0, 0, 0);
#pragma unroll
  for (int i = 0; i < 4; ++i)
#pragma unroll
    for (int j = 0; j < 2; ++j)
      acc[i][j] = __builtin_amdgcn_mfma_f32_32x32x16_bf16(a1[i], b1[j], acc[i][j], 0, 0, 0);
  __builtin_amdgcn_s_setprio(0);
}

// Fills acc for the 256x256 tile at (m0, n0). A:[M][1024], B:[Nrows][1024].
__device__ __forceinline__ void gemm_core(const __bf16* __restrict__ A,
                                          const __bf16* __restrict__ B,
                                          __bf16* sm, long m0, long n0,
                                          f32x16 (&acc)[4][2]) {
  const int t = threadIdx.x;
  const int w = t >> 6;
  const int lane = t & 63;
  const int c31 = lane & 31;
  const int hi = lane >> 5;
  const int wr = w >> 2;  // 0..1 (M)
  const int wc = w & 3;   // 0..3 (N)

  // staging source: lane l covers LDS row w*16+(l>>2), phys slot l&3, which
  // must hold logical chunk (l&3) ^ key2(row); key2 = ((l>>3)&3) ^ (w&3).
  const int l = lane;
  const int stg_row = w * 16 + (l >> 2);
  const int stg_col = ((l & 3) ^ ((l >> 3) & 3) ^ (w & 3)) << 3;
  const __bf16* pa = A + (m0 + stg_row) * KD + stg_col;
  const __bf16* pb = B + (n0 + stg_row) * KD + stg_col;
  __bf16* smw = sm + w * 512;  // wave-uniform LDS base (1024B per wave-instr)

  // fragment read offsets. key_base = ((c31>>1)&3) ^ ((c31>>4)&1); frag idx
  // parity flips key by 2 (row bit 5 via r>>4). o1 = o0 ^ 16 elems.
  const int key_base = ((c31 >> 1) & 3) ^ ((c31 >> 4) & 1);
  const int o0 = (hi ^ key_base) << 3;
  const int o1 = o0 ^ 16;
  const int aRow = (wr * 128 + c31) * 32;          // + i*1024
  const int bRow = 8192 + (wc * 64 + c31) * 32;    // + j*1024

#pragma unroll
  for (int i = 0; i < 4; ++i)
#pragma unroll
    for (int j = 0; j < 2; ++j)
      acc[i][j] = (f32x16){0.f, 0.f, 0.f, 0.f, 0.f, 0.f, 0.f, 0.f,
                           0.f, 0.f, 0.f, 0.f, 0.f, 0.f, 0.f, 0.f};

  // prologue: stage tiles 0,1
  stage_tile<0>(pa, pb, smw);
  stage_tile<1>(pa, pb, smw);

  // tiles 0..29: compute buf t%3, stage tile t+2 into buf (t+2)%3
  for (int it = 0; it < 10; ++it) {
    WAITB(4); stage_tile<2>(pa, pb, smw);
    compute_tile<0>(sm, aRow, bRow, o0, o1, acc);
    WAITB(4); stage_tile<0>(pa, pb, smw);
    compute_tile<1>(sm, aRow, bRow, o0, o1, acc);
    WAITB(4); stage_tile<1>(pa, pb, smw);
    compute_tile<2>(sm, aRow, bRow, o0, o1, acc);
  }
  // tail: tiles 30 (buf0), 31 (buf1)
  WAITB(4); compute_tile<0>(sm, aRow, bRow, o0, o1, acc);
  WAITB(0); compute_tile<1>(sm, aRow, bRow, o0, o1, acc);
}

// ---------------- GEMM1: Y = X @ W1''^T, paired-silu epilogue -> G bf16 -----
__global__ __launch_bounds__(512, 2)
void gemm1_silu(const __bf16* __restrict__ X, const __bf16* __restrict__ W1i,
                const float* __restrict__ in_b, __bf16* __restrict__ G) {
  __shared__ __bf16 sm[3 * BUF_ELEMS];
  // XCD-aware bijective swizzle: nwg = 128*8 = 1024, divisible by 8
  const int bid = blockIdx.x;
  const int swz = (bid & 7) * 128 + (bid >> 3);
  const long m0 = (long)(swz >> 3) * 256;
  const long n0 = (long)(swz & 7) * 256;

  f32x16 acc[4][2];
  gemm_core(X, W1i, sm, m0, n0, acc);

  const int lane = threadIdx.x & 63;
  const int w = threadIdx.x >> 6;
  const int wr = w >> 2, wc = w & 3;
  const int c31 = lane & 31;
  const int hi = lane >> 5;

  // G column for this wave's frag pair: even block j=0 (x_val), odd j=1 (res)
  const int gc = ((int)n0 >> 1) + wc * 32 + c31;
  const float bx = in_b[gc];
  const float br = in_b[1024 + gc];

#pragma unroll
  for (int i = 0; i < 4; ++i)
#pragma unroll
    for (int reg = 0; reg < 16; ++reg) {
      const int row = wr * 128 + i * 32 + (reg & 3) + 8 * (reg >> 2) + 4 * hi;
      float xv = acc[i][0][reg] + bx;
      float rs = acc[i][1][reg] + br;
      float e1 = __expf(-xv);
      float e2 = __expf(-rs);
      float g = xv * rs * __builtin_amdgcn_rcpf((1.0f + e1) * (1.0f + e2));
      G[(m0 + row) * 1024 + gc] = (__bf16)g;
    }
}

// ---------------- GEMM2: OUT = G @ W2^T + out_b (fp32) ----------------
__global__ __launch_bounds__(512, 2)
void gemm2_bias(const __bf16* __restrict__ G, const __bf16* __restrict__ W2,
                const float* __restrict__ out_b, float* __restrict__ OUT) {
  __shared__ __bf16 sm[3 * BUF_ELEMS];
  // nwg = 128*4 = 512, divisible by 8
  const int bid = blockIdx.x;
  const int swz = (bid & 7) * 64 + (bid >> 3);
  const long m0 = (long)(swz >> 2) * 256;
  const long n0 = (long)(swz & 3) * 256;

  f32x16 acc[4][2];
  gemm_core(G, W2, sm, m0, n0, acc);

  const int lane = threadIdx.x & 63;
  const int w = threadIdx.x >> 6;
  const int wr = w >> 2, wc = w & 3;
  const int c31 = lane & 31;
  const int hi = lane >> 5;

  float ob[2];
#pragma unroll
  for (int j = 0; j < 2; ++j)
    ob[j] = out_b[(int)n0 + wc * 64 + j * 32 + c31];
#pragma unroll
  for (int i = 0; i < 4; ++i)
#pragma unroll
    for (int j = 0; j < 2; ++j)
#pragma unroll
      for (int reg = 0; reg < 16; ++reg) {
        const int row = wr * 128 + i * 32 + (reg & 3) + 8 * (reg >> 2) + 4 * hi;
        const int col = (int)n0 + wc * 64 + j * 32 + c31;
        OUT[(m0 + row) * 1024 + col] = acc[i][j][reg] + ob[j];
      }
}

extern "C" void kernel_launch(void* const* d_in, const int* in_sizes, int n_in,
                              void* d_out, int out_size, void* d_ws, size_t ws_size,
                              hipStream_t stream) {
  const float* x = (const float*)d_in[0];
  const float* in_w = (const float*)d_in[1];
  const float* in_b = (const float*)d_in[2];
  const float* out_w = (const float*)d_in[3];
  const float* out_b = (const float*)d_in[4];
  // d_in[5..8] (dt_w, dt_b, A, Dp) are dead in the reference.

  char* ws = (char*)d_ws;
  __bf16* xb = (__bf16*)(ws);                       // 67108864 B
  __bf16* w1b = (__bf16*)(ws + (size_t)67108864);   //  4194304 B (blk32 interleaved)
  __bf16* w2b = (__bf16*)(ws + (size_t)71303168);   //  2097152 B
  __bf16* gb = (__bf16*)(ws + (size_t)73400320);    // 67108864 B

  cast_all<<<dim3(17920), 256, 0, stream>>>(x, xb, in_w, w1b, out_w, w2b);
  gemm1_silu<<<dim3(1024), 512, 0, stream>>>(xb, w1b, in_b, gb);
  gemm2_bias<<<dim3(512), 512, 0, stream>>>(gb, w2b, out_b, (float*)d_out);
}